// Round 13
// baseline (272.588 us; speedup 1.0000x reference)
//
#include <hip/hip_runtime.h>

#define USER_NUM 100000
#define ITEM_NUM 50000
#define FDIM 64
#define N_EDGES 1600000
#define BATCH 4096
#define ROWS_TOTAL (USER_NUM + ITEM_NUM)   // unified rows: users then items
#define BROWS 512                           // rows per bucket
#define NB ((ROWS_TOTAL + BROWS - 1) / BROWS)  // 293
#define CHUNK_E 2048                        // edges per passA WG
#define ENT_PER_WG (2 * CHUNK_E)
#define CAPB 20480                          // fixed entries per bucket region in edgesA
#define EDS_CAP 1024                        // LDS edge-stage capacity (4 rows; avg ~130)

__device__ __forceinline__ unsigned short f2bf(float f) {
    unsigned u = __float_as_uint(f);
    unsigned r = (u + 0x7FFFu + ((u >> 16) & 1u)) >> 16;  // RNE
    return (unsigned short)r;
}
__device__ __forceinline__ float bf2f(unsigned short h) {
    return __uint_as_float(((unsigned)h) << 16);
}
__device__ __forceinline__ float bf2f_lo(unsigned u) {   // low ushort as bf16
    return __uint_as_float(u << 16);
}
__device__ __forceinline__ float bf2f_hi(unsigned u) {   // high ushort as bf16
    return __uint_as_float(u & 0xFFFF0000u);
}

__global__ void zero_ints(int* __restrict__ a, int n) {
    int i = blockIdx.x * blockDim.x + threadIdx.x;
    if (i < n) a[i] = 0;
}

// one launch converts both tables (user then item)
__global__ void f32_to_bf16_k(const float* __restrict__ xu, const float* __restrict__ xi,
                              unsigned short* __restrict__ yu, unsigned short* __restrict__ yi,
                              int nU4, int nTot4) {
    int i = blockIdx.x * blockDim.x + threadIdx.x;
    if (i >= nTot4) return;
    const float* x = (i < nU4) ? xu : xi;
    unsigned short* y = (i < nU4) ? yu : yi;
    int k = (i < nU4) ? i : i - nU4;
    float4 v = reinterpret_cast<const float4*>(x)[k];
    reinterpret_cast<ushort4*>(y)[k] =
        make_ushort4(f2bf(v.x), f2bf(v.y), f2bf(v.z), f2bf(v.w));
}

// passA: per-WG counting sort of 2048 edges into fixed-stride bucket regions
__global__ __launch_bounds__(256) void passA(const int* __restrict__ eu,
                                             const int* __restrict__ ei,
                                             const float* __restrict__ vals,
                                             int* __restrict__ bucket_cur,
                                             int2* __restrict__ edgesA, int n) {
    __shared__ int hist[NB];
    __shared__ int lbase[NB];
    __shared__ int lcur[NB];
    __shared__ int gbase[NB];
    __shared__ int2 stage[ENT_PER_WG];
    __shared__ unsigned short sbkt[ENT_PER_WG];
    __shared__ int scan_tmp[256];

    int t = threadIdx.x;
    int e0 = blockIdx.x * CHUNK_E;
    for (int i = t; i < NB; i += 256) hist[i] = 0;
    __syncthreads();

    int myu[8], myi[8];
    float myv[8];
#pragma unroll
    for (int j = 0; j < 8; ++j) {
        int e = e0 + j * 256 + t;
        if (e < n) {
            myu[j] = eu[e]; myi[j] = ei[e]; myv[j] = vals[e];
            atomicAdd(&hist[myu[j] >> 9], 1);
            atomicAdd(&hist[(myi[j] + USER_NUM) >> 9], 1);
        } else myu[j] = -1;
    }
    __syncthreads();

    int a0 = (2 * t     < NB) ? hist[2 * t]     : 0;
    int a1 = (2 * t + 1 < NB) ? hist[2 * t + 1] : 0;
    scan_tmp[t] = a0 + a1;
    __syncthreads();
    for (int off = 1; off < 256; off <<= 1) {
        int x = (t >= off) ? scan_tmp[t - off] : 0;
        __syncthreads();
        scan_tmp[t] += x;
        __syncthreads();
    }
    int tb = (t == 0) ? 0 : scan_tmp[t - 1];
    if (2 * t < NB)     { lbase[2 * t] = tb;          lcur[2 * t] = 0; }
    if (2 * t + 1 < NB) { lbase[2 * t + 1] = tb + a0; lcur[2 * t + 1] = 0; }
    __syncthreads();

#pragma unroll
    for (int j = 0; j < 8; ++j) {
        if (myu[j] >= 0) {
            int vb = __float_as_int(myv[j]);
            int row = myu[j];
            int b = row >> 9;
            int x = ((row & 511) << 17) | myi[j];
            int p = lbase[b] + atomicAdd(&lcur[b], 1);
            stage[p] = make_int2(x, vb); sbkt[p] = (unsigned short)b;

            row = myi[j] + USER_NUM;
            b = row >> 9;
            x = ((row & 511) << 17) | myu[j];
            p = lbase[b] + atomicAdd(&lcur[b], 1);
            stage[p] = make_int2(x, vb); sbkt[p] = (unsigned short)b;
        }
    }
    __syncthreads();

    // reserve range in the bucket's fixed-stride region (one atomic per bucket)
    for (int b = t; b < NB; b += 256) {
        int nb = hist[b];
        gbase[b] = nb ? (b * CAPB + atomicAdd(&bucket_cur[b], nb)) : 0;
    }
    __syncthreads();

    int nedge = n - e0; if (nedge > CHUNK_E) nedge = CHUNK_E;
    int total = 2 * nedge;
    for (int s = t; s < total; s += 256) {
        int b = sbkt[s];
        edgesA[gbase[b] + (s - lbase[b])] = stage[s];
    }
}

// scan of per-bucket counts -> contiguous output bases brp[NB]; rp tail
__global__ void bucket_scan(const int* __restrict__ cnt, int* __restrict__ brp,
                            int* __restrict__ rp) {
    __shared__ int sh[512];
    int t = threadIdx.x;
    int v = (t < NB) ? min(cnt[t], CAPB) : 0;
    sh[t] = v;
    __syncthreads();
    for (int off = 1; off < 512; off <<= 1) {
        int x = (t >= off) ? sh[t - off] : 0;
        __syncthreads();
        sh[t] += x;
        __syncthreads();
    }
    int ex = (t == 0) ? 0 : sh[t - 1];
    if (t < NB) brp[t] = ex;
    if (t == 511) rp[ROWS_TOTAL] = sh[511];
}

// passB (512 threads): one WG per bucket; sort region by local row, emit rp
__global__ __launch_bounds__(512) void passB(const int2* __restrict__ edgesA,
                                             const int* __restrict__ cnt,
                                             const int* __restrict__ brp,
                                             int* __restrict__ rp,
                                             int2* __restrict__ edgesB) {
    __shared__ int lcnt[BROWS];
    __shared__ int lbase[BROWS];
    __shared__ int sh[512];
    int b = blockIdx.x, t = threadIdx.x;
    int n = min(cnt[b], CAPB);
    int in0 = b * CAPB;
    int o0 = brp[b];
    lcnt[t] = 0;
    __syncthreads();
    for (int s = t; s < n; s += 512)
        atomicAdd(&lcnt[edgesA[in0 + s].x >> 17], 1);
    __syncthreads();
    int v = lcnt[t];
    sh[t] = v;
    __syncthreads();
    for (int off = 1; off < 512; off <<= 1) {
        int x = (t >= off) ? sh[t - off] : 0;
        __syncthreads();
        sh[t] += x;
        __syncthreads();
    }
    lbase[t] = sh[t] - v;   // exclusive
    __syncthreads();
    int gr = b * BROWS + t;
    if (gr < ROWS_TOTAL) rp[gr] = o0 + lbase[t];
    lcnt[t] = 0;            // reuse as cursors
    __syncthreads();
    for (int s = t; s < n; s += 512) {
        int2 ent = edgesA[in0 + s];
        int rl = ent.x >> 17;
        int pos = o0 + lbase[rl] + atomicAdd(&lcnt[rl], 1);
        edgesB[pos] = ent;
    }
}

__device__ __forceinline__ int2 load_scaled(const int2* __restrict__ p, int i) {
    int2 a = p[i];
    a.x = (a.x & 0x1FFFF) << 7;   // byte offset = col * FDIM * 2
    return a;
}

// unified full gather: block-level LDS edge staging (pre-scaled byte offsets);
// quarter-wave layout: each lane covers 4 features (ushort4 = 8B), the wave's
// four 16-lane quarters process 4 different edges concurrently. Merge with
// shfl_xor(16) + shfl_xor(32).
__global__ __launch_bounds__(256) void spmm_gather(
        const unsigned short* __restrict__ ut,
        const unsigned short* __restrict__ it,
        const float* __restrict__ d_i, const float* __restrict__ d_j,
        const int2* __restrict__ edges, const int* __restrict__ rp,
        unsigned short* __restrict__ uo, unsigned short* __restrict__ io) {
    __shared__ int2 eds[EDS_CAP];
    __shared__ int srp[5];
    int t = threadIdx.x;
    int r0 = blockIdx.x * 4;           // ROWS_TOTAL % 4 == 0
    if (t < 5) srp[t] = rp[r0 + t];
    __syncthreads();
    int s0 = srp[0];
    int nent = srp[4] - s0;
    bool lds_ok = (nent <= EDS_CAP);
    if (lds_ok) {
        for (int i = t; i < nent; i += 256) eds[i] = load_scaled(edges, s0 + i);
    }
    int e  = srp[t >> 6];
    int e2 = srp[(t >> 6) + 1];
    __syncthreads();

    int r = r0 + (t >> 6);
    int lane = t & 63;
    int q  = lane >> 4;         // 0..3: which edge of the quad
    int sl = lane & 15;         // feature-quad index: features 4sl..4sl+3
    bool isU = r < USER_NUM;
    const unsigned short* xsrc  = isU ? it : ut;
    const unsigned short* xself = isU ? ut : it;
    int selfrow = isU ? r : r - USER_NUM;
    float dsc = isU ? d_i[selfrow] : d_j[selfrow];
    const char* xbase = reinterpret_cast<const char*>(xsrc) + 8 * sl;

    float accx = 0.f, accy = 0.f, accz = 0.f, accw = 0.f;
    if (q == 0) {
        uint2 s = *reinterpret_cast<const uint2*>(
            xself + (size_t)selfrow * FDIM + 4 * sl);
        accx = dsc * bf2f_lo(s.x);
        accy = dsc * bf2f_hi(s.x);
        accz = dsc * bf2f_lo(s.y);
        accw = dsc * bf2f_hi(s.y);
    }

#define FMA4(VB, XV)                                                         \
    {                                                                        \
        float v_ = __int_as_float(VB);                                       \
        accx = fmaf(v_, bf2f_lo((XV).x), accx);                              \
        accy = fmaf(v_, bf2f_hi((XV).x), accy);                              \
        accz = fmaf(v_, bf2f_lo((XV).y), accz);                              \
        accw = fmaf(v_, bf2f_hi((XV).y), accw);                              \
    }

#define GATHER_LADDER(EAT)                                                   \
    /* 8-deep, 4 edges per step = 32 edges in flight per wave */             \
    for (; e + 31 < e2; e += 32) {                                           \
        int2 ed[8];                                                          \
        uint2 xv[8];                                                         \
        _Pragma("unroll")                                                    \
        for (int j = 0; j < 8; ++j) ed[j] = EAT(e + 4 * j + q);              \
        _Pragma("unroll")                                                    \
        for (int j = 0; j < 8; ++j)                                          \
            xv[j] = *reinterpret_cast<const uint2*>(xbase + ed[j].x);        \
        _Pragma("unroll")                                                    \
        for (int j = 0; j < 8; ++j) FMA4(ed[j].y, xv[j])                     \
    }                                                                        \
    /* 4-deep, 4 edges per step */                                           \
    for (; e + 15 < e2; e += 16) {                                           \
        int2 ed[4];                                                          \
        uint2 xv[4];                                                         \
        _Pragma("unroll")                                                    \
        for (int j = 0; j < 4; ++j) ed[j] = EAT(e + 4 * j + q);              \
        _Pragma("unroll")                                                    \
        for (int j = 0; j < 4; ++j)                                          \
            xv[j] = *reinterpret_cast<const uint2*>(xbase + ed[j].x);        \
        _Pragma("unroll")                                                    \
        for (int j = 0; j < 4; ++j) FMA4(ed[j].y, xv[j])                     \
    }                                                                        \
    /* quad steps */                                                         \
    for (; e + 3 < e2; e += 4) {                                             \
        int2 a = EAT(e + q);                                                 \
        uint2 x = *reinterpret_cast<const uint2*>(xbase + a.x);              \
        FMA4(a.y, x)                                                         \
    }                                                                        \
    /* tail: quarters q < rem process edge e+q */                            \
    if (e < e2 && q < (e2 - e)) {                                            \
        int2 a = EAT(e + q);                                                 \
        uint2 x = *reinterpret_cast<const uint2*>(xbase + a.x);              \
        FMA4(a.y, x)                                                         \
    }

#define EAT_LDS(i) eds[(i) - s0]
#define EAT_GBL(i) load_scaled(edges, i)
    if (lds_ok) {
        GATHER_LADDER(EAT_LDS)
    } else {
        GATHER_LADDER(EAT_GBL)
    }
#undef EAT_LDS
#undef EAT_GBL
#undef GATHER_LADDER
#undef FMA4

    // merge the four quarters (feature sets identical across quarters)
    accx += __shfl_xor(accx, 16, 64);
    accy += __shfl_xor(accy, 16, 64);
    accz += __shfl_xor(accz, 16, 64);
    accw += __shfl_xor(accw, 16, 64);
    accx += __shfl_xor(accx, 32, 64);
    accy += __shfl_xor(accy, 32, 64);
    accz += __shfl_xor(accz, 32, 64);
    accw += __shfl_xor(accw, 32, 64);

    if (q == 0) {
        unsigned short* outp = isU ? uo : io;
        uint2 packed;
        packed.x = (unsigned)f2bf(accx) | ((unsigned)f2bf(accy) << 16);
        packed.y = (unsigned)f2bf(accz) | ((unsigned)f2bf(accw) << 16);
        *reinterpret_cast<uint2*>(outp + (size_t)selfrow * FDIM + 4 * sl) = packed;
    }
}

// per-row partial layer-3 gather, 4-deep pipelined (head only, ~330K edges)
__device__ __forceinline__ float layer3_row(const unsigned short* __restrict__ src2,
                                            float dsc, float self2,
                                            const int2* __restrict__ edges,
                                            int e, int e2, int lane) {
    float acc = dsc * self2;
    for (; e + 3 < e2; e += 4) {
        int2 ed[4];
        float xv[4];
#pragma unroll
        for (int j = 0; j < 4; ++j) ed[j] = edges[e + j];
#pragma unroll
        for (int j = 0; j < 4; ++j)
            xv[j] = bf2f(src2[(size_t)(ed[j].x & 0x1FFFF) * FDIM + lane]);
#pragma unroll
        for (int j = 0; j < 4; ++j)
            acc = fmaf(__int_as_float(ed[j].y), xv[j], acc);
    }
    for (; e < e2; ++e) {
        int2 a = edges[e];
        acc = fmaf(__int_as_float(a.y), bf2f(src2[(size_t)(a.x & 0x1FFFF) * FDIM + lane]), acc);
    }
    return acc;
}

// fused head: computes layer-3 rows on the fly (only batch rows need them)
__global__ void batch_pred_fused(const unsigned short* __restrict__ u0,
                                 const unsigned short* __restrict__ u1,
                                 const unsigned short* __restrict__ u2,
                                 const unsigned short* __restrict__ i0,
                                 const unsigned short* __restrict__ i1,
                                 const unsigned short* __restrict__ i2,
                                 const float* __restrict__ d_i, const float* __restrict__ d_j,
                                 const int2* __restrict__ edges, const int* __restrict__ rp,
                                 const int* __restrict__ user, const int* __restrict__ item_i,
                                 const int* __restrict__ item_j,
                                 float* __restrict__ pred_i, float* __restrict__ pred_j,
                                 float* __restrict__ l2_terms, float* __restrict__ lsg_terms) {
    int b = blockIdx.x * (blockDim.x >> 6) + (threadIdx.x >> 6);
    if (b >= BATCH) return;
    int lane = threadIdx.x & 63;
    int uu = user[b], ii = item_i[b], ij = item_j[b];

    float ue0 = bf2f(u0[(size_t)uu * FDIM + lane]);
    float ue1 = bf2f(u1[(size_t)uu * FDIM + lane]);
    float ue2 = bf2f(u2[(size_t)uu * FDIM + lane]);
    float vi0 = bf2f(i0[(size_t)ii * FDIM + lane]);
    float vi1 = bf2f(i1[(size_t)ii * FDIM + lane]);
    float vi2 = bf2f(i2[(size_t)ii * FDIM + lane]);
    float vj0 = bf2f(i0[(size_t)ij * FDIM + lane]);
    float vj1 = bf2f(i1[(size_t)ij * FDIM + lane]);
    float vj2 = bf2f(i2[(size_t)ij * FDIM + lane]);

    float ue3 = layer3_row(i2, d_i[uu], ue2, edges, rp[uu], rp[uu + 1], lane);
    int ri = USER_NUM + ii, rj = USER_NUM + ij;
    float vi3 = layer3_row(u2, d_j[ii], vi2, edges, rp[ri], rp[ri + 1], lane);
    float vj3 = layer3_row(u2, d_j[ij], vj2, edges, rp[rj], rp[rj + 1], lane);

    float pi = ue0 * vi0 + ue1 * vi1 + ue2 * vi2 + ue3 * vi3;
    float pj = ue0 * vj0 + ue1 * vj1 + ue2 * vj2 + ue3 * vj3;
    float l2 = ue0 * ue0 + ue1 * ue1 + ue2 * ue2 + ue3 * ue3
             + vi0 * vi0 + vi1 * vi1 + vi2 * vi2 + vi3 * vi3
             + vj0 * vj0 + vj1 * vj1 + vj2 * vj2 + vj3 * vj3;
#pragma unroll
    for (int m = 32; m >= 1; m >>= 1) {
        pi += __shfl_xor(pi, m, 64);
        pj += __shfl_xor(pj, m, 64);
        l2 += __shfl_xor(l2, m, 64);
    }
    if (lane == 0) {
        pred_i[b] = pi;
        pred_j[b] = pj;
        l2_terms[b] = 0.01f * l2;
        float x = pi - pj;
        lsg_terms[b] = fminf(x, 0.f) - log1pf(expf(-fabsf(x)));
    }
}

__global__ void final_reduce(const float* __restrict__ l2_terms,
                             const float* __restrict__ lsg_terms,
                             float* __restrict__ out_loss, float* __restrict__ out_loss2) {
    __shared__ float s1[256];
    __shared__ float s2[256];
    int t = threadIdx.x;
    float a = 0.f, b = 0.f;
    for (int i = t; i < BATCH; i += 256) { a += l2_terms[i]; b += lsg_terms[i]; }
    s1[t] = a; s2[t] = b;
    __syncthreads();
    for (int s = 128; s >= 1; s >>= 1) {
        if (t < s) { s1[t] += s1[t + s]; s2[t] += s2[t + s]; }
        __syncthreads();
    }
    if (t == 0) {
        float loss2 = -s2[0] / (float)BATCH;
        *out_loss = loss2 + s1[0] / (float)BATCH;
        *out_loss2 = loss2;
    }
}

extern "C" void kernel_launch(void* const* d_in, const int* in_sizes, int n_in,
                              void* d_out, int out_size, void* d_ws, size_t ws_size,
                              hipStream_t stream) {
    const float* eu      = (const float*)d_in[0];
    const float* ei      = (const float*)d_in[1];
    const float* d_i     = (const float*)d_in[2];
    const float* d_j     = (const float*)d_in[3];
    const float* vals    = (const float*)d_in[4];
    const int*   e_users = (const int*)d_in[5];
    const int*   e_items = (const int*)d_in[6];
    const int*   user    = (const int*)d_in[7];
    const int*   item_i  = (const int*)d_in[8];
    const int*   item_j  = (const int*)d_in[9];

    float* ws = (float*)d_ws;
    size_t off = 0;
    const size_t UW = (size_t)USER_NUM * FDIM / 2;
    const size_t IW = (size_t)ITEM_NUM * FDIM / 2;
    unsigned short* ub[3];
    unsigned short* ib[3];
    for (int k = 0; k < 3; ++k) { ub[k] = (unsigned short*)(ws + off); off += UW; }
    for (int k = 0; k < 3; ++k) { ib[k] = (unsigned short*)(ws + off); off += IW; }
    float* l2t  = ws + off; off += BATCH;
    float* lsgt = ws + off; off += BATCH;
    int* bucket_cur = (int*)(ws + off); off += 512;
    int* brp        = (int*)(ws + off); off += 512;
    int* rp         = (int*)(ws + off); off += ROWS_TOTAL + 16;
    int2* edgesA = (int2*)(ws + off); off += (size_t)2 * NB * CAPB;   // 48 MB
    int2* edgesB = (int2*)(ws + off); off += (size_t)4 * N_EDGES;

    float* outp   = (float*)d_out;
    float* pred_i = outp;
    float* pred_j = outp + BATCH;
    float* loss   = outp + 2 * BATCH;
    float* loss2  = loss + 1;

    dim3 blk(256);

    int nU4 = USER_NUM * FDIM / 4, nI4 = ITEM_NUM * FDIM / 4;
    f32_to_bf16_k<<<(nU4 + nI4 + 255) / 256, blk, 0, stream>>>(eu, ei, ub[0], ib[0], nU4, nU4 + nI4);

    zero_ints<<<1, 512, 0, stream>>>(bucket_cur, NB);
    passA<<<(N_EDGES + CHUNK_E - 1) / CHUNK_E, blk, 0, stream>>>(
        e_users, e_items, vals, bucket_cur, edgesA, N_EDGES);
    bucket_scan<<<1, 512, 0, stream>>>(bucket_cur, brp, rp);
    passB<<<NB, 512, 0, stream>>>(edgesA, bucket_cur, brp, rp, edgesB);

    // layers 1 and 2, full gathers (4 rows per block, LDS edge staging)
    int gridG = ROWS_TOTAL / 4;
    for (int k = 0; k < 2; ++k) {
        spmm_gather<<<gridG, blk, 0, stream>>>(ub[k], ib[k], d_i, d_j,
                                               edgesB, rp, ub[k + 1], ib[k + 1]);
    }

    // layer 3 computed only for batch rows, fused into the head
    batch_pred_fused<<<(BATCH + 3) / 4, blk, 0, stream>>>(
        ub[0], ub[1], ub[2], ib[0], ib[1], ib[2],
        d_i, d_j, edgesB, rp, user, item_i, item_j,
        pred_i, pred_j, l2t, lsgt);
    final_reduce<<<1, 256, 0, stream>>>(l2t, lsgt, loss, loss2);
}

// Round 14
// 255.580 us; speedup vs baseline: 1.0665x; 1.0665x over previous
//
#include <hip/hip_runtime.h>

#define USER_NUM 100000
#define ITEM_NUM 50000
#define FDIM 64
#define N_EDGES 1600000
#define BATCH 4096
#define ROWS_TOTAL (USER_NUM + ITEM_NUM)   // unified rows: users then items
#define BROWS 512                           // rows per bucket
#define NB ((ROWS_TOTAL + BROWS - 1) / BROWS)  // 293
#define CHUNK_E 2048                        // edges per passA WG
#define ENT_PER_WG (2 * CHUNK_E)
#define CAPB 20480                          // fixed entries per bucket region in edgesA
#define EDS_CAP 1024                        // LDS edge-stage capacity (4 rows; avg ~130)

__device__ __forceinline__ unsigned short f2bf(float f) {
    unsigned u = __float_as_uint(f);
    unsigned r = (u + 0x7FFFu + ((u >> 16) & 1u)) >> 16;  // RNE
    return (unsigned short)r;
}
__device__ __forceinline__ float bf2f(unsigned short h) {
    return __uint_as_float(((unsigned)h) << 16);
}
__device__ __forceinline__ float bf2f_lo(unsigned u) {   // low ushort as bf16
    return __uint_as_float(u << 16);
}
__device__ __forceinline__ float bf2f_hi(unsigned u) {   // high ushort as bf16
    return __uint_as_float(u & 0xFFFF0000u);
}

__global__ void zero_ints(int* __restrict__ a, int n) {
    int i = blockIdx.x * blockDim.x + threadIdx.x;
    if (i < n) a[i] = 0;
}

// one launch converts both tables (user then item)
__global__ void f32_to_bf16_k(const float* __restrict__ xu, const float* __restrict__ xi,
                              unsigned short* __restrict__ yu, unsigned short* __restrict__ yi,
                              int nU4, int nTot4) {
    int i = blockIdx.x * blockDim.x + threadIdx.x;
    if (i >= nTot4) return;
    const float* x = (i < nU4) ? xu : xi;
    unsigned short* y = (i < nU4) ? yu : yi;
    int k = (i < nU4) ? i : i - nU4;
    float4 v = reinterpret_cast<const float4*>(x)[k];
    reinterpret_cast<ushort4*>(y)[k] =
        make_ushort4(f2bf(v.x), f2bf(v.y), f2bf(v.z), f2bf(v.w));
}

// passA: per-WG counting sort of 2048 edges into fixed-stride bucket regions
__global__ __launch_bounds__(256) void passA(const int* __restrict__ eu,
                                             const int* __restrict__ ei,
                                             const float* __restrict__ vals,
                                             int* __restrict__ bucket_cur,
                                             int2* __restrict__ edgesA, int n) {
    __shared__ int hist[NB];
    __shared__ int lbase[NB];
    __shared__ int lcur[NB];
    __shared__ int gbase[NB];
    __shared__ int2 stage[ENT_PER_WG];
    __shared__ unsigned short sbkt[ENT_PER_WG];
    __shared__ int scan_tmp[256];

    int t = threadIdx.x;
    int e0 = blockIdx.x * CHUNK_E;
    for (int i = t; i < NB; i += 256) hist[i] = 0;
    __syncthreads();

    int myu[8], myi[8];
    float myv[8];
#pragma unroll
    for (int j = 0; j < 8; ++j) {
        int e = e0 + j * 256 + t;
        if (e < n) {
            myu[j] = eu[e]; myi[j] = ei[e]; myv[j] = vals[e];
            atomicAdd(&hist[myu[j] >> 9], 1);
            atomicAdd(&hist[(myi[j] + USER_NUM) >> 9], 1);
        } else myu[j] = -1;
    }
    __syncthreads();

    int a0 = (2 * t     < NB) ? hist[2 * t]     : 0;
    int a1 = (2 * t + 1 < NB) ? hist[2 * t + 1] : 0;
    scan_tmp[t] = a0 + a1;
    __syncthreads();
    for (int off = 1; off < 256; off <<= 1) {
        int x = (t >= off) ? scan_tmp[t - off] : 0;
        __syncthreads();
        scan_tmp[t] += x;
        __syncthreads();
    }
    int tb = (t == 0) ? 0 : scan_tmp[t - 1];
    if (2 * t < NB)     { lbase[2 * t] = tb;          lcur[2 * t] = 0; }
    if (2 * t + 1 < NB) { lbase[2 * t + 1] = tb + a0; lcur[2 * t + 1] = 0; }
    __syncthreads();

#pragma unroll
    for (int j = 0; j < 8; ++j) {
        if (myu[j] >= 0) {
            int vb = __float_as_int(myv[j]);
            int row = myu[j];
            int b = row >> 9;
            int x = ((row & 511) << 17) | myi[j];
            int p = lbase[b] + atomicAdd(&lcur[b], 1);
            stage[p] = make_int2(x, vb); sbkt[p] = (unsigned short)b;

            row = myi[j] + USER_NUM;
            b = row >> 9;
            x = ((row & 511) << 17) | myu[j];
            p = lbase[b] + atomicAdd(&lcur[b], 1);
            stage[p] = make_int2(x, vb); sbkt[p] = (unsigned short)b;
        }
    }
    __syncthreads();

    // reserve range in the bucket's fixed-stride region (one atomic per bucket)
    for (int b = t; b < NB; b += 256) {
        int nb = hist[b];
        gbase[b] = nb ? (b * CAPB + atomicAdd(&bucket_cur[b], nb)) : 0;
    }
    __syncthreads();

    int nedge = n - e0; if (nedge > CHUNK_E) nedge = CHUNK_E;
    int total = 2 * nedge;
    for (int s = t; s < total; s += 256) {
        int b = sbkt[s];
        edgesA[gbase[b] + (s - lbase[b])] = stage[s];
    }
}

// scan of per-bucket counts -> contiguous output bases brp[NB]; rp tail
__global__ void bucket_scan(const int* __restrict__ cnt, int* __restrict__ brp,
                            int* __restrict__ rp) {
    __shared__ int sh[512];
    int t = threadIdx.x;
    int v = (t < NB) ? min(cnt[t], CAPB) : 0;
    sh[t] = v;
    __syncthreads();
    for (int off = 1; off < 512; off <<= 1) {
        int x = (t >= off) ? sh[t - off] : 0;
        __syncthreads();
        sh[t] += x;
        __syncthreads();
    }
    int ex = (t == 0) ? 0 : sh[t - 1];
    if (t < NB) brp[t] = ex;
    if (t == 511) rp[ROWS_TOTAL] = sh[511];
}

// passB (512 threads): one WG per bucket; sort region by local row, emit rp
__global__ __launch_bounds__(512) void passB(const int2* __restrict__ edgesA,
                                             const int* __restrict__ cnt,
                                             const int* __restrict__ brp,
                                             int* __restrict__ rp,
                                             int2* __restrict__ edgesB) {
    __shared__ int lcnt[BROWS];
    __shared__ int lbase[BROWS];
    __shared__ int sh[512];
    int b = blockIdx.x, t = threadIdx.x;
    int n = min(cnt[b], CAPB);
    int in0 = b * CAPB;
    int o0 = brp[b];
    lcnt[t] = 0;
    __syncthreads();
    for (int s = t; s < n; s += 512)
        atomicAdd(&lcnt[edgesA[in0 + s].x >> 17], 1);
    __syncthreads();
    int v = lcnt[t];
    sh[t] = v;
    __syncthreads();
    for (int off = 1; off < 512; off <<= 1) {
        int x = (t >= off) ? sh[t - off] : 0;
        __syncthreads();
        sh[t] += x;
        __syncthreads();
    }
    lbase[t] = sh[t] - v;   // exclusive
    __syncthreads();
    int gr = b * BROWS + t;
    if (gr < ROWS_TOTAL) rp[gr] = o0 + lbase[t];
    lcnt[t] = 0;            // reuse as cursors
    __syncthreads();
    for (int s = t; s < n; s += 512) {
        int2 ent = edgesA[in0 + s];
        int rl = ent.x >> 17;
        int pos = o0 + lbase[rl] + atomicAdd(&lcnt[rl], 1);
        edgesB[pos] = ent;
    }
}

__device__ __forceinline__ int2 load_scaled(const int2* __restrict__ p, int i) {
    int2 a = p[i];
    a.x = (a.x & 0x1FFFF) << 7;   // byte offset = col * FDIM * 2
    return a;
}

// unified full gather (round-12 proven): block-level LDS edge staging with
// pre-scaled byte-offset columns; per-wave 8/4/1 ladder, half-wave x ushort2.
__global__ __launch_bounds__(256) void spmm_gather(
        const unsigned short* __restrict__ ut,
        const unsigned short* __restrict__ it,
        const float* __restrict__ d_i, const float* __restrict__ d_j,
        const int2* __restrict__ edges, const int* __restrict__ rp,
        unsigned short* __restrict__ uo, unsigned short* __restrict__ io) {
    __shared__ int2 eds[EDS_CAP];
    __shared__ int srp[5];
    int t = threadIdx.x;
    int r0 = blockIdx.x * 4;           // ROWS_TOTAL % 4 == 0
    if (t < 5) srp[t] = rp[r0 + t];
    __syncthreads();
    int s0 = srp[0];
    int nent = srp[4] - s0;
    bool lds_ok = (nent <= EDS_CAP);
    if (lds_ok) {
        for (int i = t; i < nent; i += 256) eds[i] = load_scaled(edges, s0 + i);
    }
    int e  = srp[t >> 6];
    int e2 = srp[(t >> 6) + 1];
    __syncthreads();

    int r = r0 + (t >> 6);
    int lane = t & 63;
    int half = lane >> 5;       // 0 or 1: which edge of the pair
    int sl = lane & 31;         // feature-pair index: features 2sl, 2sl+1
    bool isU = r < USER_NUM;
    const unsigned short* xsrc  = isU ? it : ut;
    const unsigned short* xself = isU ? ut : it;
    int selfrow = isU ? r : r - USER_NUM;
    float dsc = isU ? d_i[selfrow] : d_j[selfrow];
    const char* xbase = reinterpret_cast<const char*>(xsrc) + 4 * sl;

    float accx = 0.f, accy = 0.f;
    if (half == 0) {
        unsigned s = *reinterpret_cast<const unsigned*>(
            xself + (size_t)selfrow * FDIM + 2 * sl);
        accx = dsc * bf2f_lo(s);
        accy = dsc * bf2f_hi(s);
    }

#define GATHER_LADDER(EAT)                                                   \
    /* 8-deep, 2 edges per step = 16 edges in flight */                      \
    for (; e + 15 < e2; e += 16) {                                           \
        int2 ed[8];                                                          \
        unsigned xv[8];                                                      \
        _Pragma("unroll")                                                    \
        for (int j = 0; j < 8; ++j) ed[j] = EAT(e + 2 * j + half);           \
        _Pragma("unroll")                                                    \
        for (int j = 0; j < 8; ++j)                                          \
            xv[j] = *reinterpret_cast<const unsigned*>(xbase + ed[j].x);     \
        _Pragma("unroll")                                                    \
        for (int j = 0; j < 8; ++j) {                                        \
            float v = __int_as_float(ed[j].y);                               \
            accx = fmaf(v, bf2f_lo(xv[j]), accx);                            \
            accy = fmaf(v, bf2f_hi(xv[j]), accy);                            \
        }                                                                    \
    }                                                                        \
    /* 4-deep, 2 edges per step */                                           \
    for (; e + 7 < e2; e += 8) {                                             \
        int2 ed[4];                                                          \
        unsigned xv[4];                                                      \
        _Pragma("unroll")                                                    \
        for (int j = 0; j < 4; ++j) ed[j] = EAT(e + 2 * j + half);           \
        _Pragma("unroll")                                                    \
        for (int j = 0; j < 4; ++j)                                          \
            xv[j] = *reinterpret_cast<const unsigned*>(xbase + ed[j].x);     \
        _Pragma("unroll")                                                    \
        for (int j = 0; j < 4; ++j) {                                        \
            float v = __int_as_float(ed[j].y);                               \
            accx = fmaf(v, bf2f_lo(xv[j]), accx);                            \
            accy = fmaf(v, bf2f_hi(xv[j]), accy);                            \
        }                                                                    \
    }                                                                        \
    /* pair tail */                                                          \
    for (; e + 1 < e2; e += 2) {                                             \
        int2 a = EAT(e + half);                                              \
        unsigned x = *reinterpret_cast<const unsigned*>(xbase + a.x);        \
        float v = __int_as_float(a.y);                                       \
        accx = fmaf(v, bf2f_lo(x), accx);                                    \
        accy = fmaf(v, bf2f_hi(x), accy);                                    \
    }                                                                        \
    /* odd last edge: half 0 only */                                         \
    if (e < e2 && half == 0) {                                               \
        int2 a = EAT(e);                                                     \
        unsigned x = *reinterpret_cast<const unsigned*>(xbase + a.x);        \
        float v = __int_as_float(a.y);                                       \
        accx = fmaf(v, bf2f_lo(x), accx);                                    \
        accy = fmaf(v, bf2f_hi(x), accy);                                    \
    }

#define EAT_LDS(i) eds[(i) - s0]
#define EAT_GBL(i) load_scaled(edges, i)
    if (lds_ok) {
        GATHER_LADDER(EAT_LDS)
    } else {
        GATHER_LADDER(EAT_GBL)
    }
#undef EAT_LDS
#undef EAT_GBL
#undef GATHER_LADDER

    // merge the two halves (feature sets are identical across halves)
    accx += __shfl_xor(accx, 32, 64);
    accy += __shfl_xor(accy, 32, 64);

    if (half == 0) {
        unsigned short* outp = isU ? uo : io;
        unsigned packed = (unsigned)f2bf(accx) | ((unsigned)f2bf(accy) << 16);
        *reinterpret_cast<unsigned*>(outp + (size_t)selfrow * FDIM + 2 * sl) = packed;
    }
}

// per-row partial layer-3 gather, 4-deep pipelined (head only, ~330K edges)
__device__ __forceinline__ float layer3_row(const unsigned short* __restrict__ src2,
                                            float dsc, float self2,
                                            const int2* __restrict__ edges,
                                            int e, int e2, int lane) {
    float acc = dsc * self2;
    for (; e + 3 < e2; e += 4) {
        int2 ed[4];
        float xv[4];
#pragma unroll
        for (int j = 0; j < 4; ++j) ed[j] = edges[e + j];
#pragma unroll
        for (int j = 0; j < 4; ++j)
            xv[j] = bf2f(src2[(size_t)(ed[j].x & 0x1FFFF) * FDIM + lane]);
#pragma unroll
        for (int j = 0; j < 4; ++j)
            acc = fmaf(__int_as_float(ed[j].y), xv[j], acc);
    }
    for (; e < e2; ++e) {
        int2 a = edges[e];
        acc = fmaf(__int_as_float(a.y), bf2f(src2[(size_t)(a.x & 0x1FFFF) * FDIM + lane]), acc);
    }
    return acc;
}

// fused head: computes layer-3 rows on the fly (only batch rows need them)
__global__ void batch_pred_fused(const unsigned short* __restrict__ u0,
                                 const unsigned short* __restrict__ u1,
                                 const unsigned short* __restrict__ u2,
                                 const unsigned short* __restrict__ i0,
                                 const unsigned short* __restrict__ i1,
                                 const unsigned short* __restrict__ i2,
                                 const float* __restrict__ d_i, const float* __restrict__ d_j,
                                 const int2* __restrict__ edges, const int* __restrict__ rp,
                                 const int* __restrict__ user, const int* __restrict__ item_i,
                                 const int* __restrict__ item_j,
                                 float* __restrict__ pred_i, float* __restrict__ pred_j,
                                 float* __restrict__ l2_terms, float* __restrict__ lsg_terms) {
    int b = blockIdx.x * (blockDim.x >> 6) + (threadIdx.x >> 6);
    if (b >= BATCH) return;
    int lane = threadIdx.x & 63;
    int uu = user[b], ii = item_i[b], ij = item_j[b];

    float ue0 = bf2f(u0[(size_t)uu * FDIM + lane]);
    float ue1 = bf2f(u1[(size_t)uu * FDIM + lane]);
    float ue2 = bf2f(u2[(size_t)uu * FDIM + lane]);
    float vi0 = bf2f(i0[(size_t)ii * FDIM + lane]);
    float vi1 = bf2f(i1[(size_t)ii * FDIM + lane]);
    float vi2 = bf2f(i2[(size_t)ii * FDIM + lane]);
    float vj0 = bf2f(i0[(size_t)ij * FDIM + lane]);
    float vj1 = bf2f(i1[(size_t)ij * FDIM + lane]);
    float vj2 = bf2f(i2[(size_t)ij * FDIM + lane]);

    float ue3 = layer3_row(i2, d_i[uu], ue2, edges, rp[uu], rp[uu + 1], lane);
    int ri = USER_NUM + ii, rj = USER_NUM + ij;
    float vi3 = layer3_row(u2, d_j[ii], vi2, edges, rp[ri], rp[ri + 1], lane);
    float vj3 = layer3_row(u2, d_j[ij], vj2, edges, rp[rj], rp[rj + 1], lane);

    float pi = ue0 * vi0 + ue1 * vi1 + ue2 * vi2 + ue3 * vi3;
    float pj = ue0 * vj0 + ue1 * vj1 + ue2 * vj2 + ue3 * vj3;
    float l2 = ue0 * ue0 + ue1 * ue1 + ue2 * ue2 + ue3 * ue3
             + vi0 * vi0 + vi1 * vi1 + vi2 * vi2 + vi3 * vi3
             + vj0 * vj0 + vj1 * vj1 + vj2 * vj2 + vj3 * vj3;
#pragma unroll
    for (int m = 32; m >= 1; m >>= 1) {
        pi += __shfl_xor(pi, m, 64);
        pj += __shfl_xor(pj, m, 64);
        l2 += __shfl_xor(l2, m, 64);
    }
    if (lane == 0) {
        pred_i[b] = pi;
        pred_j[b] = pj;
        l2_terms[b] = 0.01f * l2;
        float x = pi - pj;
        lsg_terms[b] = fminf(x, 0.f) - log1pf(expf(-fabsf(x)));
    }
}

__global__ void final_reduce(const float* __restrict__ l2_terms,
                             const float* __restrict__ lsg_terms,
                             float* __restrict__ out_loss, float* __restrict__ out_loss2) {
    __shared__ float s1[256];
    __shared__ float s2[256];
    int t = threadIdx.x;
    float a = 0.f, b = 0.f;
    for (int i = t; i < BATCH; i += 256) { a += l2_terms[i]; b += lsg_terms[i]; }
    s1[t] = a; s2[t] = b;
    __syncthreads();
    for (int s = 128; s >= 1; s >>= 1) {
        if (t < s) { s1[t] += s1[t + s]; s2[t] += s2[t + s]; }
        __syncthreads();
    }
    if (t == 0) {
        float loss2 = -s2[0] / (float)BATCH;
        *out_loss = loss2 + s1[0] / (float)BATCH;
        *out_loss2 = loss2;
    }
}

extern "C" void kernel_launch(void* const* d_in, const int* in_sizes, int n_in,
                              void* d_out, int out_size, void* d_ws, size_t ws_size,
                              hipStream_t stream) {
    const float* eu      = (const float*)d_in[0];
    const float* ei      = (const float*)d_in[1];
    const float* d_i     = (const float*)d_in[2];
    const float* d_j     = (const float*)d_in[3];
    const float* vals    = (const float*)d_in[4];
    const int*   e_users = (const int*)d_in[5];
    const int*   e_items = (const int*)d_in[6];
    const int*   user    = (const int*)d_in[7];
    const int*   item_i  = (const int*)d_in[8];
    const int*   item_j  = (const int*)d_in[9];

    float* ws = (float*)d_ws;
    size_t off = 0;
    const size_t UW = (size_t)USER_NUM * FDIM / 2;
    const size_t IW = (size_t)ITEM_NUM * FDIM / 2;
    unsigned short* ub[3];
    unsigned short* ib[3];
    for (int k = 0; k < 3; ++k) { ub[k] = (unsigned short*)(ws + off); off += UW; }
    for (int k = 0; k < 3; ++k) { ib[k] = (unsigned short*)(ws + off); off += IW; }
    float* l2t  = ws + off; off += BATCH;
    float* lsgt = ws + off; off += BATCH;
    int* bucket_cur = (int*)(ws + off); off += 512;
    int* brp        = (int*)(ws + off); off += 512;
    int* rp         = (int*)(ws + off); off += ROWS_TOTAL + 16;
    int2* edgesA = (int2*)(ws + off); off += (size_t)2 * NB * CAPB;   // 48 MB
    int2* edgesB = (int2*)(ws + off); off += (size_t)4 * N_EDGES;

    float* outp   = (float*)d_out;
    float* pred_i = outp;
    float* pred_j = outp + BATCH;
    float* loss   = outp + 2 * BATCH;
    float* loss2  = loss + 1;

    dim3 blk(256);

    int nU4 = USER_NUM * FDIM / 4, nI4 = ITEM_NUM * FDIM / 4;
    f32_to_bf16_k<<<(nU4 + nI4 + 255) / 256, blk, 0, stream>>>(eu, ei, ub[0], ib[0], nU4, nU4 + nI4);

    zero_ints<<<1, 512, 0, stream>>>(bucket_cur, NB);
    passA<<<(N_EDGES + CHUNK_E - 1) / CHUNK_E, blk, 0, stream>>>(
        e_users, e_items, vals, bucket_cur, edgesA, N_EDGES);
    bucket_scan<<<1, 512, 0, stream>>>(bucket_cur, brp, rp);
    passB<<<NB, 512, 0, stream>>>(edgesA, bucket_cur, brp, rp, edgesB);

    // layers 1 and 2, full gathers (4 rows per block, LDS edge staging)
    int gridG = ROWS_TOTAL / 4;
    for (int k = 0; k < 2; ++k) {
        spmm_gather<<<gridG, blk, 0, stream>>>(ub[k], ib[k], d_i, d_j,
                                               edgesB, rp, ub[k + 1], ib[k + 1]);
    }

    // layer 3 computed only for batch rows, fused into the head
    batch_pred_fused<<<(BATCH + 3) / 4, blk, 0, stream>>>(
        ub[0], ub[1], ub[2], ib[0], ib[1], ib[2],
        d_i, d_j, edgesB, rp, user, item_i, item_j,
        pred_i, pred_j, l2t, lsgt);
    final_reduce<<<1, 256, 0, stream>>>(l2t, lsgt, loss, loss2);
}

// Round 16
// 249.338 us; speedup vs baseline: 1.0932x; 1.0250x over previous
//
#include <hip/hip_runtime.h>

#define USER_NUM 100000
#define ITEM_NUM 50000
#define FDIM 64
#define N_EDGES 1600000
#define BATCH 4096
#define ROWS_TOTAL (USER_NUM + ITEM_NUM)   // unified rows: users then items
#define BROWS 512                           // rows per bucket
#define NB ((ROWS_TOTAL + BROWS - 1) / BROWS)  // 293
#define CHUNK_E 2048                        // edges per passA WG
#define ENT_PER_WG (2 * CHUNK_E)
#define CAPB 20480                          // fixed entries per bucket region in edgesA
#define EDS_CAP 1024                        // LDS edge-stage capacity (4 rows; avg ~130)

__device__ __forceinline__ unsigned short f2bf(float f) {
    unsigned u = __float_as_uint(f);
    unsigned r = (u + 0x7FFFu + ((u >> 16) & 1u)) >> 16;  // RNE
    return (unsigned short)r;
}
__device__ __forceinline__ float bf2f(unsigned short h) {
    return __uint_as_float(((unsigned)h) << 16);
}
__device__ __forceinline__ float bf2f_lo(unsigned u) {   // low ushort as bf16
    return __uint_as_float(u << 16);
}
__device__ __forceinline__ float bf2f_hi(unsigned u) {   // high ushort as bf16
    return __uint_as_float(u & 0xFFFF0000u);
}

// one launch converts both tables (user then item); also zeroes bucket_cur
__global__ void f32_to_bf16_k(const float* __restrict__ xu, const float* __restrict__ xi,
                              unsigned short* __restrict__ yu, unsigned short* __restrict__ yi,
                              int* __restrict__ bucket_cur, int nU4, int nTot4) {
    int i = blockIdx.x * blockDim.x + threadIdx.x;
    if (i < 512) bucket_cur[i] = 0;
    if (i >= nTot4) return;
    const float* x = (i < nU4) ? xu : xi;
    unsigned short* y = (i < nU4) ? yu : yi;
    int k = (i < nU4) ? i : i - nU4;
    float4 v = reinterpret_cast<const float4*>(x)[k];
    reinterpret_cast<ushort4*>(y)[k] =
        make_ushort4(f2bf(v.x), f2bf(v.y), f2bf(v.z), f2bf(v.w));
}

// passA: per-WG counting sort of 2048 edges into fixed-stride bucket regions
__global__ __launch_bounds__(256) void passA(const int* __restrict__ eu,
                                             const int* __restrict__ ei,
                                             const float* __restrict__ vals,
                                             int* __restrict__ bucket_cur,
                                             int2* __restrict__ edgesA, int n) {
    __shared__ int hist[NB];
    __shared__ int lbase[NB];
    __shared__ int lcur[NB];
    __shared__ int gbase[NB];
    __shared__ int2 stage[ENT_PER_WG];
    __shared__ unsigned short sbkt[ENT_PER_WG];
    __shared__ int scan_tmp[256];

    int t = threadIdx.x;
    int e0 = blockIdx.x * CHUNK_E;
    for (int i = t; i < NB; i += 256) hist[i] = 0;
    __syncthreads();

    int myu[8], myi[8];
    float myv[8];
#pragma unroll
    for (int j = 0; j < 8; ++j) {
        int e = e0 + j * 256 + t;
        if (e < n) {
            myu[j] = eu[e]; myi[j] = ei[e]; myv[j] = vals[e];
            atomicAdd(&hist[myu[j] >> 9], 1);
            atomicAdd(&hist[(myi[j] + USER_NUM) >> 9], 1);
        } else myu[j] = -1;
    }
    __syncthreads();

    int a0 = (2 * t     < NB) ? hist[2 * t]     : 0;
    int a1 = (2 * t + 1 < NB) ? hist[2 * t + 1] : 0;
    scan_tmp[t] = a0 + a1;
    __syncthreads();
    for (int off = 1; off < 256; off <<= 1) {
        int x = (t >= off) ? scan_tmp[t - off] : 0;
        __syncthreads();
        scan_tmp[t] += x;
        __syncthreads();
    }
    int tb = (t == 0) ? 0 : scan_tmp[t - 1];
    if (2 * t < NB)     { lbase[2 * t] = tb;          lcur[2 * t] = 0; }
    if (2 * t + 1 < NB) { lbase[2 * t + 1] = tb + a0; lcur[2 * t + 1] = 0; }
    __syncthreads();

#pragma unroll
    for (int j = 0; j < 8; ++j) {
        if (myu[j] >= 0) {
            int vb = __float_as_int(myv[j]);
            int row = myu[j];
            int b = row >> 9;
            int x = ((row & 511) << 17) | myi[j];
            int p = lbase[b] + atomicAdd(&lcur[b], 1);
            stage[p] = make_int2(x, vb); sbkt[p] = (unsigned short)b;

            row = myi[j] + USER_NUM;
            b = row >> 9;
            x = ((row & 511) << 17) | myu[j];
            p = lbase[b] + atomicAdd(&lcur[b], 1);
            stage[p] = make_int2(x, vb); sbkt[p] = (unsigned short)b;
        }
    }
    __syncthreads();

    // reserve range in the bucket's fixed-stride region (one atomic per bucket)
    for (int b = t; b < NB; b += 256) {
        int nb = hist[b];
        gbase[b] = nb ? (b * CAPB + atomicAdd(&bucket_cur[b], nb)) : 0;
    }
    __syncthreads();

    int nedge = n - e0; if (nedge > CHUNK_E) nedge = CHUNK_E;
    int total = 2 * nedge;
    for (int s = t; s < total; s += 256) {
        int b = sbkt[s];
        edgesA[gbase[b] + (s - lbase[b])] = stage[s];
    }
}

// scan of per-bucket counts -> contiguous output bases brp[NB]; rp tail
__global__ void bucket_scan(const int* __restrict__ cnt, int* __restrict__ brp,
                            int* __restrict__ rp) {
    __shared__ int sh[512];
    int t = threadIdx.x;
    int v = (t < NB) ? min(cnt[t], CAPB) : 0;
    sh[t] = v;
    __syncthreads();
    for (int off = 1; off < 512; off <<= 1) {
        int x = (t >= off) ? sh[t - off] : 0;
        __syncthreads();
        sh[t] += x;
        __syncthreads();
    }
    int ex = (t == 0) ? 0 : sh[t - 1];
    if (t < NB) brp[t] = ex;
    if (t == 511) rp[ROWS_TOTAL] = sh[511];
}

// passB (512 threads): one WG per bucket; sort region by local row, emit rp.
// Output entries packed to 4B: (val_bf16_lo15 << 17) | col17 (vals are >= 0).
__global__ __launch_bounds__(512) void passB(const int2* __restrict__ edgesA,
                                             const int* __restrict__ cnt,
                                             const int* __restrict__ brp,
                                             int* __restrict__ rp,
                                             unsigned* __restrict__ edgesB) {
    __shared__ int lcnt[BROWS];
    __shared__ int lbase[BROWS];
    __shared__ int sh[512];
    int b = blockIdx.x, t = threadIdx.x;
    int n = min(cnt[b], CAPB);
    int in0 = b * CAPB;
    int o0 = brp[b];
    lcnt[t] = 0;
    __syncthreads();
    for (int s = t; s < n; s += 512)
        atomicAdd(&lcnt[edgesA[in0 + s].x >> 17], 1);
    __syncthreads();
    int v = lcnt[t];
    sh[t] = v;
    __syncthreads();
    for (int off = 1; off < 512; off <<= 1) {
        int x = (t >= off) ? sh[t - off] : 0;
        __syncthreads();
        sh[t] += x;
        __syncthreads();
    }
    lbase[t] = sh[t] - v;   // exclusive
    __syncthreads();
    int gr = b * BROWS + t;
    if (gr < ROWS_TOTAL) rp[gr] = o0 + lbase[t];
    lcnt[t] = 0;            // reuse as cursors
    __syncthreads();
    for (int s = t; s < n; s += 512) {
        int2 ent = edgesA[in0 + s];
        int rl = ent.x >> 17;
        int pos = o0 + lbase[rl] + atomicAdd(&lcnt[rl], 1);
        unsigned packed = (((unsigned)f2bf(__int_as_float(ent.y)) & 0x7FFFu) << 17)
                        | ((unsigned)ent.x & 0x1FFFFu);
        edgesB[pos] = packed;
    }
}

// decode 4B packed entry -> (byte offset, f32 val bits)
__device__ __forceinline__ int2 decode_packed(const unsigned* __restrict__ p, int i) {
    unsigned x = p[i];
    int2 a;
    a.x = (int)((x & 0x1FFFFu) << 7);        // byte offset = col * FDIM * 2
    a.y = (int)((x >> 17) << 16);            // f32 bits of bf16 val (sign 0)
    return a;
}

// unified full gather (proven r12/r14 ladder): block-level LDS edge staging;
// packed 4B global entries decoded once during staging, hot ladder unchanged.
__global__ __launch_bounds__(256) void spmm_gather(
        const unsigned short* __restrict__ ut,
        const unsigned short* __restrict__ it,
        const float* __restrict__ d_i, const float* __restrict__ d_j,
        const unsigned* __restrict__ edges, const int* __restrict__ rp,
        unsigned short* __restrict__ uo, unsigned short* __restrict__ io) {
    __shared__ int2 eds[EDS_CAP];
    __shared__ int srp[5];
    int t = threadIdx.x;
    int r0 = blockIdx.x * 4;           // ROWS_TOTAL % 4 == 0
    if (t < 5) srp[t] = rp[r0 + t];
    __syncthreads();
    int s0 = srp[0];
    int nent = srp[4] - s0;
    bool lds_ok = (nent <= EDS_CAP);
    if (lds_ok) {
        for (int i = t; i < nent; i += 256) eds[i] = decode_packed(edges, s0 + i);
    }
    int e  = srp[t >> 6];
    int e2 = srp[(t >> 6) + 1];
    __syncthreads();

    int r = r0 + (t >> 6);
    int lane = t & 63;
    int half = lane >> 5;       // 0 or 1: which edge of the pair
    int sl = lane & 31;         // feature-pair index: features 2sl, 2sl+1
    bool isU = r < USER_NUM;
    const unsigned short* xsrc  = isU ? it : ut;
    const unsigned short* xself = isU ? ut : it;
    int selfrow = isU ? r : r - USER_NUM;
    float dsc = isU ? d_i[selfrow] : d_j[selfrow];
    const char* xbase = reinterpret_cast<const char*>(xsrc) + 4 * sl;

    float accx = 0.f, accy = 0.f;
    if (half == 0) {
        unsigned s = *reinterpret_cast<const unsigned*>(
            xself + (size_t)selfrow * FDIM + 2 * sl);
        accx = dsc * bf2f_lo(s);
        accy = dsc * bf2f_hi(s);
    }

#define GATHER_LADDER(EAT)                                                   \
    /* 8-deep, 2 edges per step = 16 edges in flight */                      \
    for (; e + 15 < e2; e += 16) {                                           \
        int2 ed[8];                                                          \
        unsigned xv[8];                                                      \
        _Pragma("unroll")                                                    \
        for (int j = 0; j < 8; ++j) ed[j] = EAT(e + 2 * j + half);           \
        _Pragma("unroll")                                                    \
        for (int j = 0; j < 8; ++j)                                          \
            xv[j] = *reinterpret_cast<const unsigned*>(xbase + ed[j].x);     \
        _Pragma("unroll")                                                    \
        for (int j = 0; j < 8; ++j) {                                        \
            float v = __int_as_float(ed[j].y);                               \
            accx = fmaf(v, bf2f_lo(xv[j]), accx);                            \
            accy = fmaf(v, bf2f_hi(xv[j]), accy);                            \
        }                                                                    \
    }                                                                        \
    /* 4-deep, 2 edges per step */                                           \
    for (; e + 7 < e2; e += 8) {                                             \
        int2 ed[4];                                                          \
        unsigned xv[4];                                                      \
        _Pragma("unroll")                                                    \
        for (int j = 0; j < 4; ++j) ed[j] = EAT(e + 2 * j + half);           \
        _Pragma("unroll")                                                    \
        for (int j = 0; j < 4; ++j)                                          \
            xv[j] = *reinterpret_cast<const unsigned*>(xbase + ed[j].x);     \
        _Pragma("unroll")                                                    \
        for (int j = 0; j < 4; ++j) {                                        \
            float v = __int_as_float(ed[j].y);                               \
            accx = fmaf(v, bf2f_lo(xv[j]), accx);                            \
            accy = fmaf(v, bf2f_hi(xv[j]), accy);                            \
        }                                                                    \
    }                                                                        \
    /* pair tail */                                                          \
    for (; e + 1 < e2; e += 2) {                                             \
        int2 a = EAT(e + half);                                              \
        unsigned x = *reinterpret_cast<const unsigned*>(xbase + a.x);        \
        float v = __int_as_float(a.y);                                       \
        accx = fmaf(v, bf2f_lo(x), accx);                                    \
        accy = fmaf(v, bf2f_hi(x), accy);                                    \
    }                                                                        \
    /* odd last edge: half 0 only */                                         \
    if (e < e2 && half == 0) {                                               \
        int2 a = EAT(e);                                                     \
        unsigned x = *reinterpret_cast<const unsigned*>(xbase + a.x);        \
        float v = __int_as_float(a.y);                                       \
        accx = fmaf(v, bf2f_lo(x), accx);                                    \
        accy = fmaf(v, bf2f_hi(x), accy);                                    \
    }

#define EAT_LDS(i) eds[(i) - s0]
#define EAT_GBL(i) decode_packed(edges, i)
    if (lds_ok) {
        GATHER_LADDER(EAT_LDS)
    } else {
        GATHER_LADDER(EAT_GBL)
    }
#undef EAT_LDS
#undef EAT_GBL
#undef GATHER_LADDER

    // merge the two halves (feature sets are identical across halves)
    accx += __shfl_xor(accx, 32, 64);
    accy += __shfl_xor(accy, 32, 64);

    if (half == 0) {
        unsigned short* outp = isU ? uo : io;
        unsigned packed = (unsigned)f2bf(accx) | ((unsigned)f2bf(accy) << 16);
        *reinterpret_cast<unsigned*>(outp + (size_t)selfrow * FDIM + 2 * sl) = packed;
    }
}

// per-row partial layer-3 gather (head only, ~330K edges), packed entries
__device__ __forceinline__ float layer3_row(const unsigned short* __restrict__ src2,
                                            float dsc, float self2,
                                            const unsigned* __restrict__ edges,
                                            int e, int e2, int lane) {
    float acc = dsc * self2;
    for (; e + 3 < e2; e += 4) {
        unsigned ed[4];
        float xv[4];
#pragma unroll
        for (int j = 0; j < 4; ++j) ed[j] = edges[e + j];
#pragma unroll
        for (int j = 0; j < 4; ++j)
            xv[j] = bf2f(src2[(size_t)(ed[j] & 0x1FFFFu) * FDIM + lane]);
#pragma unroll
        for (int j = 0; j < 4; ++j)
            acc = fmaf(__uint_as_float((ed[j] >> 17) << 16), xv[j], acc);
    }
    for (; e < e2; ++e) {
        unsigned a = edges[e];
        acc = fmaf(__uint_as_float((a >> 17) << 16),
                   bf2f(src2[(size_t)(a & 0x1FFFFu) * FDIM + lane]), acc);
    }
    return acc;
}

// fused head: computes layer-3 rows on the fly (only batch rows need them)
__global__ void batch_pred_fused(const unsigned short* __restrict__ u0,
                                 const unsigned short* __restrict__ u1,
                                 const unsigned short* __restrict__ u2,
                                 const unsigned short* __restrict__ i0,
                                 const unsigned short* __restrict__ i1,
                                 const unsigned short* __restrict__ i2,
                                 const float* __restrict__ d_i, const float* __restrict__ d_j,
                                 const unsigned* __restrict__ edges, const int* __restrict__ rp,
                                 const int* __restrict__ user, const int* __restrict__ item_i,
                                 const int* __restrict__ item_j,
                                 float* __restrict__ pred_i, float* __restrict__ pred_j,
                                 float* __restrict__ l2_terms, float* __restrict__ lsg_terms) {
    int b = blockIdx.x * (blockDim.x >> 6) + (threadIdx.x >> 6);
    if (b >= BATCH) return;
    int lane = threadIdx.x & 63;
    int uu = user[b], ii = item_i[b], ij = item_j[b];

    float ue0 = bf2f(u0[(size_t)uu * FDIM + lane]);
    float ue1 = bf2f(u1[(size_t)uu * FDIM + lane]);
    float ue2 = bf2f(u2[(size_t)uu * FDIM + lane]);
    float vi0 = bf2f(i0[(size_t)ii * FDIM + lane]);
    float vi1 = bf2f(i1[(size_t)ii * FDIM + lane]);
    float vi2 = bf2f(i2[(size_t)ii * FDIM + lane]);
    float vj0 = bf2f(i0[(size_t)ij * FDIM + lane]);
    float vj1 = bf2f(i1[(size_t)ij * FDIM + lane]);
    float vj2 = bf2f(i2[(size_t)ij * FDIM + lane]);

    float ue3 = layer3_row(i2, d_i[uu], ue2, edges, rp[uu], rp[uu + 1], lane);
    int ri = USER_NUM + ii, rj = USER_NUM + ij;
    float vi3 = layer3_row(u2, d_j[ii], vi2, edges, rp[ri], rp[ri + 1], lane);
    float vj3 = layer3_row(u2, d_j[ij], vj2, edges, rp[rj], rp[rj + 1], lane);

    float pi = ue0 * vi0 + ue1 * vi1 + ue2 * vi2 + ue3 * vi3;
    float pj = ue0 * vj0 + ue1 * vj1 + ue2 * vj2 + ue3 * vj3;
    float l2 = ue0 * ue0 + ue1 * ue1 + ue2 * ue2 + ue3 * ue3
             + vi0 * vi0 + vi1 * vi1 + vi2 * vi2 + vi3 * vi3
             + vj0 * vj0 + vj1 * vj1 + vj2 * vj2 + vj3 * vj3;
#pragma unroll
    for (int m = 32; m >= 1; m >>= 1) {
        pi += __shfl_xor(pi, m, 64);
        pj += __shfl_xor(pj, m, 64);
        l2 += __shfl_xor(l2, m, 64);
    }
    if (lane == 0) {
        pred_i[b] = pi;
        pred_j[b] = pj;
        l2_terms[b] = 0.01f * l2;
        float x = pi - pj;
        lsg_terms[b] = fminf(x, 0.f) - log1pf(expf(-fabsf(x)));
    }
}

__global__ void final_reduce(const float* __restrict__ l2_terms,
                             const float* __restrict__ lsg_terms,
                             float* __restrict__ out_loss, float* __restrict__ out_loss2) {
    __shared__ float s1[256];
    __shared__ float s2[256];
    int t = threadIdx.x;
    float a = 0.f, b = 0.f;
    for (int i = t; i < BATCH; i += 256) { a += l2_terms[i]; b += lsg_terms[i]; }
    s1[t] = a; s2[t] = b;
    __syncthreads();
    for (int s = 128; s >= 1; s >>= 1) {
        if (t < s) { s1[t] += s1[t + s]; s2[t] += s2[t + s]; }
        __syncthreads();
    }
    if (t == 0) {
        float loss2 = -s2[0] / (float)BATCH;
        *out_loss = loss2 + s1[0] / (float)BATCH;
        *out_loss2 = loss2;
    }
}

extern "C" void kernel_launch(void* const* d_in, const int* in_sizes, int n_in,
                              void* d_out, int out_size, void* d_ws, size_t ws_size,
                              hipStream_t stream) {
    const float* eu      = (const float*)d_in[0];
    const float* ei      = (const float*)d_in[1];
    const float* d_i     = (const float*)d_in[2];
    const float* d_j     = (const float*)d_in[3];
    const float* vals    = (const float*)d_in[4];
    const int*   e_users = (const int*)d_in[5];
    const int*   e_items = (const int*)d_in[6];
    const int*   user    = (const int*)d_in[7];
    const int*   item_i  = (const int*)d_in[8];
    const int*   item_j  = (const int*)d_in[9];

    float* ws = (float*)d_ws;
    size_t off = 0;
    const size_t UW = (size_t)USER_NUM * FDIM / 2;
    const size_t IW = (size_t)ITEM_NUM * FDIM / 2;
    unsigned short* ub[3];
    unsigned short* ib[3];
    for (int k = 0; k < 3; ++k) { ub[k] = (unsigned short*)(ws + off); off += UW; }
    for (int k = 0; k < 3; ++k) { ib[k] = (unsigned short*)(ws + off); off += IW; }
    float* l2t  = ws + off; off += BATCH;
    float* lsgt = ws + off; off += BATCH;
    int* bucket_cur = (int*)(ws + off); off += 512;
    int* brp        = (int*)(ws + off); off += 512;
    int* rp         = (int*)(ws + off); off += ROWS_TOTAL + 16;
    int2* edgesA    = (int2*)(ws + off); off += (size_t)2 * NB * CAPB;   // 48 MB
    unsigned* edgesB = (unsigned*)(ws + off); off += (size_t)2 * N_EDGES; // 12.8 MB

    float* outp   = (float*)d_out;
    float* pred_i = outp;
    float* pred_j = outp + BATCH;
    float* loss   = outp + 2 * BATCH;
    float* loss2  = loss + 1;

    dim3 blk(256);

    int nU4 = USER_NUM * FDIM / 4, nI4 = ITEM_NUM * FDIM / 4;
    f32_to_bf16_k<<<(nU4 + nI4 + 255) / 256, blk, 0, stream>>>(
        eu, ei, ub[0], ib[0], bucket_cur, nU4, nU4 + nI4);

    passA<<<(N_EDGES + CHUNK_E - 1) / CHUNK_E, blk, 0, stream>>>(
        e_users, e_items, vals, bucket_cur, edgesA, N_EDGES);
    bucket_scan<<<1, 512, 0, stream>>>(bucket_cur, brp, rp);
    passB<<<NB, 512, 0, stream>>>(edgesA, bucket_cur, brp, rp, edgesB);

    // layers 1 and 2, full gathers (4 rows per block, LDS edge staging)
    int gridG = ROWS_TOTAL / 4;
    for (int k = 0; k < 2; ++k) {
        spmm_gather<<<gridG, blk, 0, stream>>>(ub[k], ib[k], d_i, d_j,
                                               edgesB, rp, ub[k + 1], ib[k + 1]);
    }

    // layer 3 computed only for batch rows, fused into the head
    batch_pred_fused<<<(BATCH + 3) / 4, blk, 0, stream>>>(
        ub[0], ub[1], ub[2], ib[0], ib[1], ib[2],
        d_i, d_j, edgesB, rp, user, item_i, item_j,
        pred_i, pred_j, l2t, lsgt);
    final_reduce<<<1, 256, 0, stream>>>(l2t, lsgt, loss, loss2);
}